// Round 3
// baseline (172.139 us; speedup 1.0000x reference)
//
#include <hip/hip_runtime.h>
#include <hip/hip_bf16.h>

// Problem constants (fixed by setup_inputs)
#define BATCH 32
#define LSEQ 1025
#define TT 2048
#define NTOK 513      // 1 + (LSEQ-1)/2
#define EMB 384
#define FT 16         // frames per tile (block)
#define WMAX 104      // window span 97 frames / min token spacing 1 + margin
#define INV_SQRT_2PI 0.3989422804014327f

// ---------------------------------------------------------------------------
// Inclusive Hillis-Steele scan over NTOK elements with 256 threads.
// src/dst are LDS ping-pong buffers; returns the buffer holding the result.
// Caller must __syncthreads() after filling src.
// ---------------------------------------------------------------------------
__device__ inline float* scan513(float* src, float* dst) {
  for (int off = 1; off < NTOK; off <<= 1) {
    for (int i = threadIdx.x; i < NTOK; i += 256) {
      float v = src[i];
      if (i >= off) v += src[i - off];
      dst[i] = v;
    }
    __syncthreads();
    float* t = src; src = dst; dst = t;
  }
  return src;  // result lives here after the final swap
}

// ---------------------------------------------------------------------------
// prep: merge blank/token pairs, parallel cumsum, filter tokens that can ever
// have nonzero weight (d>=1 && tok!=PAD; d=0 underflows exactly: centers are
// int/half-int, frame midpoints x.5 -> |z|>=5e5), ordered compaction into
// 8-byte records {c, (d<<17)|tok*EMB}. Also per-batch kept count and total.
// ---------------------------------------------------------------------------
__global__ __launch_bounds__(256) void prep_kernel(
    const int* __restrict__ text, const int* __restrict__ durs,
    float2* __restrict__ kept, int* __restrict__ counts,
    float* __restrict__ totals) {
  const int b = blockIdx.x;
  const int tid = threadIdx.x;
  __shared__ float s_a[NTOK], s_b[NTOK];   // scan ping-pong
  __shared__ float s_c[NTOK];              // token centers
  __shared__ float s_d[NTOK];              // merged durations
  __shared__ int s_tok[NTOK];

  const int* tb = text + b * LSEQ;
  const int* db = durs + b * LSEQ;
  for (int n = tid; n < NTOK; n += 256) {
    int dm, tk;
    if (n == 0) { dm = db[0]; tk = tb[0]; }
    else { dm = db[2 * n - 1] + db[2 * n]; tk = tb[2 * n - 1]; }
    s_d[n] = (float)dm;
    s_a[n] = (float)dm;
    s_tok[n] = tk;
  }
  __syncthreads();
  float* cum = scan513(s_a, s_b);          // inclusive cumsum (exact: small ints)
  for (int n = tid; n < NTOK; n += 256) {
    s_c[n] = cum[n] - 0.5f * s_d[n];       // token center
  }
  if (tid == 0) totals[b] = cum[NTOK - 1];
  __syncthreads();
  // keep flags -> ordered compaction positions
  float* flagbuf = (cum == s_a) ? s_a : s_b;  // reuse whichever holds cum
  float* other = (cum == s_a) ? s_b : s_a;
  for (int n = tid; n < NTOK; n += 256) {
    flagbuf[n] = (s_d[n] >= 1.0f && s_tok[n] != 0) ? 1.0f : 0.0f;
  }
  __syncthreads();
  float* incl = scan513(flagbuf, other);
  for (int n = tid; n < NTOK; n += 256) {
    float d = s_d[n];
    int tk = s_tok[n];
    if (d >= 1.0f && tk != 0) {
      int pos = (int)incl[n] - 1;
      int packed = ((int)d << 17) | (tk * EMB);
      kept[b * NTOK + pos] = make_float2(s_c[n], __int_as_float(packed));
    }
  }
  if (tid == 0) counts[b] = (int)incl[NTOK - 1];
}

// ---------------------------------------------------------------------------
// frames: one block per (batch, 16-frame tile), 192 threads.
// thread = (frame f = tid&15, col-chunk q = tid>>4 of 32 cols).
// Reach-skip is block-uniform (one window per tile -> zero divergence).
// Per token: one register __expf per thread (its frame), wsum in a register
// (normalization needs no LDS/barrier), 8x float4 FMA with 16-lane-broadcast
// emb loads. One barrier total (after staging token params).
// ---------------------------------------------------------------------------
__global__ __launch_bounds__(192) void frames_kernel(
    const float2* __restrict__ kept, const int* __restrict__ counts,
    const float* __restrict__ totals, const float* __restrict__ emb,
    float* __restrict__ out) {
  const int t0 = blockIdx.x * FT;
  const int b = blockIdx.y;
  const int tid = threadIdx.x;
  const int f = tid & 15;
  const int q = tid >> 4;  // 0..11, 32 cols each

  __shared__ float4 s_tk[WMAX];    // {c, inv_sig, coef, off bitcast}
  __shared__ float s_reach[WMAX];  // 6.7*d (+eps): covers fp32-exp cutoff

  const int M = counts[b];
  const float total = totals[b];
  const float2* kb = kept + b * NTOK;

  // window: tokens with c in [t0-40.5, t0+56] (max reach 6.7*6 = 40.2)
  const float loB = (float)t0 - 40.5f;
  const float hiB = (float)t0 + 56.0f;
  int l = 0, r = M;
  while (l < r) { int m = (l + r) >> 1; if (kb[m].x < loB) l = m + 1; else r = m; }
  const int lo = l;
  r = M;
  while (l < r) { int m = (l + r) >> 1; if (kb[m].x <= hiB) l = m + 1; else r = m; }
  int win = l - lo;
  if (win > WMAX) win = WMAX;                      // hard bound ~99
  if ((float)t0 + 0.5f >= total) win = 0;          // tile fully invalid -> zeros

  for (int i = tid; i < win; i += 192) {
    float2 kv = kb[lo + i];
    int packed = __float_as_int(kv.y);
    int d = packed >> 17;
    int off = packed & 0x1FFFF;
    float df = (float)d;
    float inv_sig = 1.0f / (0.5f * df + 1e-6f);    // matches ref sig exactly
    s_tk[i] = make_float4(kv.x, inv_sig, INV_SQRT_2PI * inv_sig,
                          __int_as_float(off));
    s_reach[i] = 6.7f * df + 1e-4f;
  }
  __syncthreads();

  const float tf = (float)t0 + (float)f + 0.5f;    // this thread's frame midpoint
  const float tileLo = (float)t0 + 0.5f;
  const float tileHi = (float)t0 + 15.5f;

  float wsum = 0.f;
  float4 acc[8];
#pragma unroll
  for (int j = 0; j < 8; ++j) acc[j] = make_float4(0.f, 0.f, 0.f, 0.f);

  for (int n = 0; n < win; ++n) {
    const float4 tk = s_tk[n];                     // broadcast LDS read
    const float reach = s_reach[n];
    if (tk.x + reach < tileLo || tk.x - reach > tileHi) continue;  // uniform
    const float z = (tf - tk.x) * tk.y;
    const float w = tk.z * __expf(-0.5f * z * z);
    wsum += w;
    const float4* vrow = (const float4*)(emb + (__float_as_int(tk.w) & 0x1FFFF))
                         + q * 8;
#pragma unroll
    for (int j = 0; j < 8; ++j) {
      const float4 v = vrow[j];                    // 16-lane broadcast, L1/L2
      acc[j].x += w * v.x; acc[j].y += w * v.y;
      acc[j].z += w * v.z; acc[j].w += w * v.w;
    }
  }

  const float fac = (tf < total) ? 1.0f / (wsum + 1e-6f) : 0.0f;
  float4* orow = (float4*)(out + ((size_t)b * TT + t0 + f) * EMB) + q * 8;
#pragma unroll
  for (int j = 0; j < 8; ++j) {
    float4 rv;
    rv.x = acc[j].x * fac; rv.y = acc[j].y * fac;
    rv.z = acc[j].z * fac; rv.w = acc[j].w * fac;
    orow[j] = rv;
  }
}

extern "C" void kernel_launch(void* const* d_in, const int* in_sizes, int n_in,
                              void* d_out, int out_size, void* d_ws,
                              size_t ws_size, hipStream_t stream) {
  const int* text = (const int*)d_in[0];
  const int* durs = (const int*)d_in[1];
  const float* emb = (const float*)d_in[2];
  float* out = (float*)d_out;

  // workspace: kept float2[32*513] (131 KB) | counts int[32] | totals float[32]
  float2* kept = (float2*)d_ws;
  int* counts = (int*)(kept + BATCH * NTOK);
  float* totals = (float*)(counts + BATCH);

  prep_kernel<<<BATCH, 256, 0, stream>>>(text, durs, kept, counts, totals);
  frames_kernel<<<dim3(TT / FT, BATCH), 192, 0, stream>>>(kept, counts, totals,
                                                          emb, out);
}

// Round 4
// 135.277 us; speedup vs baseline: 1.2725x; 1.2725x over previous
//
#include <hip/hip_runtime.h>
#include <hip/hip_bf16.h>

// Problem constants (fixed by setup_inputs)
#define BATCH 32
#define LSEQ 1025
#define TT 2048
#define NTOK 513      // 1 + (LSEQ-1)/2
#define EMB 384
#define FT 32         // frames per tile (block)
#define WMAX 120      // window span <=113 (kept tokens are >=1 frame apart)
#define INV_SQRT_2PI 0.3989422804014327f

// ---------------------------------------------------------------------------
// Inclusive Hillis-Steele scan over NTOK elements with 256 threads.
// src/dst are LDS ping-pong buffers; returns the buffer holding the result.
// Caller must __syncthreads() after filling src.
// ---------------------------------------------------------------------------
__device__ inline float* scan513(float* src, float* dst) {
  for (int off = 1; off < NTOK; off <<= 1) {
    for (int i = threadIdx.x; i < NTOK; i += 256) {
      float v = src[i];
      if (i >= off) v += src[i - off];
      dst[i] = v;
    }
    __syncthreads();
    float* t = src; src = dst; dst = t;
  }
  return src;  // result lives here after the final swap
}

// ---------------------------------------------------------------------------
// prep: merge blank/token pairs, parallel cumsum, filter tokens that can ever
// have nonzero weight (d>=1 && tok!=PAD; d=0 underflows exactly: centers are
// int/half-int, frame midpoints x.5 -> |z|>=5e5), ordered compaction into
// 8-byte records {c, (d<<17)|tok*EMB}. Also per-batch kept count and total.
// ---------------------------------------------------------------------------
__global__ __launch_bounds__(256) void prep_kernel(
    const int* __restrict__ text, const int* __restrict__ durs,
    float2* __restrict__ kept, int* __restrict__ counts,
    float* __restrict__ totals) {
  const int b = blockIdx.x;
  const int tid = threadIdx.x;
  __shared__ float s_a[NTOK], s_b[NTOK];   // scan ping-pong
  __shared__ float s_c[NTOK];              // token centers
  __shared__ float s_d[NTOK];              // merged durations
  __shared__ int s_tok[NTOK];

  const int* tb = text + b * LSEQ;
  const int* db = durs + b * LSEQ;
  for (int n = tid; n < NTOK; n += 256) {
    int dm, tk;
    if (n == 0) { dm = db[0]; tk = tb[0]; }
    else { dm = db[2 * n - 1] + db[2 * n]; tk = tb[2 * n - 1]; }
    s_d[n] = (float)dm;
    s_a[n] = (float)dm;
    s_tok[n] = tk;
  }
  __syncthreads();
  float* cum = scan513(s_a, s_b);          // inclusive cumsum (exact: small ints)
  for (int n = tid; n < NTOK; n += 256) {
    s_c[n] = cum[n] - 0.5f * s_d[n];       // token center
  }
  if (tid == 0) totals[b] = cum[NTOK - 1];
  __syncthreads();
  // keep flags -> ordered compaction positions
  float* flagbuf = (cum == s_a) ? s_a : s_b;  // reuse whichever holds cum
  float* other = (cum == s_a) ? s_b : s_a;
  for (int n = tid; n < NTOK; n += 256) {
    flagbuf[n] = (s_d[n] >= 1.0f && s_tok[n] != 0) ? 1.0f : 0.0f;
  }
  __syncthreads();
  float* incl = scan513(flagbuf, other);
  for (int n = tid; n < NTOK; n += 256) {
    float d = s_d[n];
    int tk = s_tok[n];
    if (d >= 1.0f && tk != 0) {
      int pos = (int)incl[n] - 1;
      int packed = ((int)d << 17) | (tk * EMB);
      kept[b * NTOK + pos] = make_float2(s_c[n], __int_as_float(packed));
    }
  }
  if (tid == 0) counts[b] = (int)incl[NTOK - 1];
}

// ---------------------------------------------------------------------------
// frames: one block per (batch, 32-frame tile), 384 threads (6 waves).
// Phase 1: stage the token window params to LDS.
// Phase 2: eval dense weight matrix s_w[win][32] (one exp per pair, spread
//          over all 384 threads -> ~5 exps/thread).
// Phase 3: per-frame sums -> normalization factors.
// Phase 4 (mix): fh = tid/192 -> waves 0-2 own frames 0-15, waves 3-5 own
//          frames 16-31 (reach-skip is wave-uniform: zero divergence).
//          col2 = (tid%192)*2: per token ONE coalesced float2 emb load
//          (512 B/wave-instr), 4 broadcast ds_read_b128 for 16 weights,
//          32 FMAs. Embedding row loaded once per half-tile per block.
// ---------------------------------------------------------------------------
__global__ __launch_bounds__(384) void frames_kernel(
    const float2* __restrict__ kept, const int* __restrict__ counts,
    const float* __restrict__ totals, const float* __restrict__ emb,
    float* __restrict__ out) {
  const int t0 = blockIdx.x * FT;
  const int b = blockIdx.y;
  const int tid = threadIdx.x;

  __shared__ float4 s_tk[WMAX];    // {c, inv_sig, coef, off bitcast}
  __shared__ float s_reach[WMAX];  // 6.7*d (+eps): covers fp32-exp cutoff
  __shared__ float s_w[WMAX * FT];
  __shared__ float s_factor[FT];

  const int M = counts[b];
  const float total = totals[b];
  const float2* kb = kept + b * NTOK;

  // window: tokens with c in [t0-40.5, t0+71.5] (max reach 6.7*6 = 40.2)
  const float loB = (float)t0 - 40.5f;
  const float hiB = (float)t0 + 71.5f;
  int l = 0, r = M;
  while (l < r) { int m = (l + r) >> 1; if (kb[m].x < loB) l = m + 1; else r = m; }
  const int lo = l;
  r = M;
  while (l < r) { int m = (l + r) >> 1; if (kb[m].x <= hiB) l = m + 1; else r = m; }
  int win = l - lo;
  if (win > WMAX) win = WMAX;                      // hard bound ~113
  if ((float)t0 + 0.5f >= total) win = 0;          // tile fully invalid -> zeros

  for (int i = tid; i < win; i += 384) {
    float2 kv = kb[lo + i];
    int packed = __float_as_int(kv.y);
    int d = packed >> 17;
    int off = packed & 0x1FFFF;
    float df = (float)d;
    float inv_sig = 1.0f / (0.5f * df + 1e-6f);    // matches ref sig exactly
    s_tk[i] = make_float4(kv.x, inv_sig, INV_SQRT_2PI * inv_sig,
                          __int_as_float(off));
    s_reach[i] = 6.7f * df + 1e-4f;
  }
  __syncthreads();

  // dense weight eval: one mul + one exp per (token, frame)
  const float t0f = (float)t0 + 0.5f;
  const int pairs = win * FT;
  for (int idx = tid; idx < pairs; idx += 384) {
    const int n = idx >> 5, f = idx & (FT - 1);
    const float4 tk = s_tk[n];
    const float z = (t0f + (float)f - tk.x) * tk.y;
    s_w[idx] = tk.z * __expf(-0.5f * z * z);
  }
  __syncthreads();

  // per-frame sums -> factor (consecutive threads hit consecutive banks)
  if (tid < FT) {
    float s = 0.f;
    for (int n = 0; n < win; ++n) s += s_w[n * FT + tid];
    const float tf = t0f + (float)tid;
    s_factor[tid] = (tf < total) ? 1.0f / (s + 1e-6f) : 0.0f;
  }
  __syncthreads();

  // mix: waves 0-2 -> frames 0-15, waves 3-5 -> frames 16-31 (wave-uniform)
  const int fh = tid / 192;
  const int c2 = (tid % 192) * 2;
  const int fbase = fh * 16;
  float2 acc[16];
#pragma unroll
  for (int k = 0; k < 16; ++k) acc[k] = make_float2(0.f, 0.f);

  const float fLo = (float)(t0 + fbase) + 0.5f;
  const float fHi = fLo + 15.0f;
  for (int n = 0; n < win; ++n) {
    const float4 tk = s_tk[n];                     // broadcast LDS read
    const float reach = s_reach[n];
    if (tk.x + reach < fLo || tk.x - reach > fHi) continue;  // wave-uniform
    const float2 v = *(const float2*)(emb + (__float_as_int(tk.w) & 0x1FFFF)
                                      + c2);       // coalesced 512 B/wave
    const float4* wp = (const float4*)(s_w + n * FT + fbase);  // 64 B aligned
#pragma unroll
    for (int q = 0; q < 4; ++q) {
      const float4 w4 = wp[q];                     // broadcast ds_read_b128
      float2& a0 = acc[4 * q + 0];
      a0.x += w4.x * v.x; a0.y += w4.x * v.y;
      float2& a1 = acc[4 * q + 1];
      a1.x += w4.y * v.x; a1.y += w4.y * v.y;
      float2& a2 = acc[4 * q + 2];
      a2.x += w4.z * v.x; a2.y += w4.z * v.y;
      float2& a3 = acc[4 * q + 3];
      a3.x += w4.w * v.x; a3.y += w4.w * v.y;
    }
  }

  // normalize + write (covers every frame incl. invalid -> zeros)
  float* obase = out + ((size_t)b * TT + t0 + fbase) * EMB + c2;
#pragma unroll
  for (int k = 0; k < 16; ++k) {
    const float fac = s_factor[fbase + k];
    *(float2*)(obase + (size_t)k * EMB) =
        make_float2(acc[k].x * fac, acc[k].y * fac);
  }
}

extern "C" void kernel_launch(void* const* d_in, const int* in_sizes, int n_in,
                              void* d_out, int out_size, void* d_ws,
                              size_t ws_size, hipStream_t stream) {
  const int* text = (const int*)d_in[0];
  const int* durs = (const int*)d_in[1];
  const float* emb = (const float*)d_in[2];
  float* out = (float*)d_out;

  // workspace: kept float2[32*513] (131 KB) | counts int[32] | totals float[32]
  float2* kept = (float2*)d_ws;
  int* counts = (int*)(kept + BATCH * NTOK);
  float* totals = (float*)(counts + BATCH);

  prep_kernel<<<BATCH, 256, 0, stream>>>(text, durs, kept, counts, totals);
  frames_kernel<<<dim3(TT / FT, BATCH), 384, 0, stream>>>(kept, counts, totals,
                                                          emb, out);
}